// Round 3
// baseline (1184.494 us; speedup 1.0000x reference)
//
#include <hip/hip_runtime.h>
#include <cstdint>

typedef __bf16 bf16;
typedef __bf16 bf16x2 __attribute__((ext_vector_type(2)));
typedef __bf16 bf16x4 __attribute__((ext_vector_type(4)));
typedef __bf16 bf16x8 __attribute__((ext_vector_type(8)));
typedef float  f32x4  __attribute__((ext_vector_type(4)));

#define DIM   4096
#define NH    32
#define NKV   8
#define HD    128
#define BATCH 2
#define SEQ   2048
#define NTOK  (BATCH * SEQ)   // 4096
#define QKVN  6144            // NH*HD + 2*NKV*HD
#define KCOFF 4096            // k column offset in qkv buffer
#define VCOFF 5120            // v column offset
#define NEG_BIG (-1e30f)

// async global->LDS, 16B per lane; LDS dest is wave-uniform base + lane*16
#define GLL16(gp, lp)                                                          \
  __builtin_amdgcn_global_load_lds(                                            \
      (__attribute__((address_space(1))) uint32_t*)(gp),                       \
      (__attribute__((address_space(3))) uint32_t*)(lp), 16, 0, 0)

// ---------------------------------------------------------------------------
// fused wq/wk/wv transpose+convert into concatenated wT[6144][4096]
__global__ __launch_bounds__(256) void transpose_cvt3(const float* __restrict__ wq,
                                                      const float* __restrict__ wk,
                                                      const float* __restrict__ wv,
                                                      bf16* __restrict__ out) {
  __shared__ float t[32][33];
  const int tx = threadIdx.x, ty = threadIdx.y;
  const int n0 = blockIdx.x * 32;  // col in concat [0,6144)
  const int k0 = blockIdx.y * 32;  // row (K dim)
  const float* src; int c0, C;
  if (n0 < 4096)      { src = wq; c0 = n0;        C = 4096; }
  else if (n0 < 5120) { src = wk; c0 = n0 - 4096; C = 1024; }
  else                { src = wv; c0 = n0 - 5120; C = 1024; }
#pragma unroll
  for (int yy = 0; yy < 32; yy += 8)
    t[ty + yy][tx] = src[(size_t)(k0 + ty + yy) * C + c0 + tx];
  __syncthreads();
#pragma unroll
  for (int yy = 0; yy < 32; yy += 8)
    out[(size_t)(n0 + ty + yy) * DIM + k0 + tx] = (bf16)t[tx][ty + yy];
}

// transpose + convert: in[R][C] f32 -> out[C][R] bf16 (for wo)
__global__ __launch_bounds__(256) void transpose_cvt(const float* __restrict__ in,
                                                     bf16* __restrict__ out,
                                                     int R, int C) {
  __shared__ float t[32][33];
  const int tx = threadIdx.x, ty = threadIdx.y;
  const int gx = blockIdx.x * 32, gy = blockIdx.y * 32;
#pragma unroll
  for (int yy = 0; yy < 32; yy += 8)
    t[ty + yy][tx] = in[(size_t)(gy + ty + yy) * C + gx + tx];
  __syncthreads();
#pragma unroll
  for (int yy = 0; yy < 32; yy += 8)
    out[(size_t)(gx + ty + yy) * R + gy + tx] = (bf16)t[tx][ty + yy];
}

// elementwise fp32 -> bf16, 4 per thread
__global__ __launch_bounds__(256) void cvt_f32_bf16(const float* __restrict__ in,
                                                    bf16* __restrict__ out) {
  size_t i = ((size_t)blockIdx.x * 256 + threadIdx.x) * 4;
  f32x4 v = *(const f32x4*)(in + i);
  bf16x4 o;
  o[0] = (bf16)v[0]; o[1] = (bf16)v[1]; o[2] = (bf16)v[2]; o[3] = (bf16)v[3];
  *(bf16x4*)(out + i) = o;
}

// ---------------------------------------------------------------------------
// m97-style GEMM + XOR-swizzled LDS (kills 8-way ds_read_b128 conflicts) +
// LDS-bounce vectorized epilogue. C[M][N] = A[M][K] @ BT[N][K]^T.
// Swizzle: 64B rows = 4 chunks of 16B; physical chunk = logical ^ ((row>>1)&3)
// -> per-phase uniform 4-deep bank coverage (optimal for b128).
template <bool OUTF32>
__global__ __launch_bounds__(256, 4) void gemm_bt(const bf16* __restrict__ A,
                                                  const bf16* __restrict__ BT,
                                                  void* __restrict__ Cout,
                                                  int M, int N, int K) {
  __shared__ bf16 ls[2 * 128 * 32];  // lA = ls, lB = ls+4096; epilogue: f32[32][128]
  bf16* lA = ls;
  bf16* lB = ls + 128 * 32;
  const int tid = threadIdx.x;
  const int w = tid >> 6, lane = tid & 63;
  const int quad = lane >> 4, lq = lane & 15;
  const int bm = blockIdx.y * 128, bn = blockIdx.x * 128;
  const int wm = (w & 1) * 64, wn = (w >> 1) * 64;
  f32x4 acc[4][4] = {};
  const bf16* aBase = A + (size_t)bm * K;
  const bf16* bBase = BT + (size_t)bn * K;
  // staging: physical chunk p = tid (+256); row = p>>2, swizzled k-offset
  const int r0 = tid >> 2, o0 = (((tid & 3) ^ ((r0 >> 1) & 3))) * 8;
  const int r1 = r0 + 64,  o1 = ((((tid + 256) & 3) ^ ((r1 >> 1) & 3))) * 8;
  const int sw = (lq >> 1) & 3;  // read-side swizzle (row>>1)&3 == (lq>>1)&3

  for (int k0 = 0; k0 < K; k0 += 32) {
    GLL16(aBase + (size_t)r0 * K + k0 + o0, lA + (w * 64) * 8);
    GLL16(aBase + (size_t)r1 * K + k0 + o1, lA + (256 + w * 64) * 8);
    GLL16(bBase + (size_t)r0 * K + k0 + o0, lB + (w * 64) * 8);
    GLL16(bBase + (size_t)r1 * K + k0 + o1, lB + (256 + w * 64) * 8);
    __syncthreads();
    bf16x8 af[4], bfr[4];
#pragma unroll
    for (int i = 0; i < 4; ++i)
      af[i] = *(const bf16x8*)(lA + (wm + i * 16 + lq) * 32 + (quad ^ sw) * 8);
#pragma unroll
    for (int j = 0; j < 4; ++j)
      bfr[j] = *(const bf16x8*)(lB + (wn + j * 16 + lq) * 32 + (quad ^ sw) * 8);
#pragma unroll
    for (int i = 0; i < 4; ++i)
#pragma unroll
      for (int j = 0; j < 4; ++j)
        acc[i][j] = __builtin_amdgcn_mfma_f32_16x16x32_bf16(af[i], bfr[j], acc[i][j], 0, 0, 0);
    __syncthreads();
  }

  // epilogue: bounce 32-row slabs through LDS -> vectorized global stores
  float* le = (float*)ls;  // 32 x 128 f32 = 16 KB
#pragma unroll
  for (int p = 0; p < 4; ++p) {
    if ((w & 1) == (p >> 1)) {
#pragma unroll
      for (int ii = 0; ii < 2; ++ii) {
        const int i = (p & 1) * 2 + ii;
#pragma unroll
        for (int j = 0; j < 4; ++j)
#pragma unroll
          for (int r = 0; r < 4; ++r)
            le[(ii * 16 + quad * 4 + r) * 128 + wn + j * 16 + lq] = acc[i][j][r];
      }
    }
    __syncthreads();
    {
      const int row_l = tid >> 3, c0 = (tid & 7) * 16;
      const size_t grow = (size_t)(bm + p * 32 + row_l) * N + bn + c0;
      if (OUTF32) {
        float* gp = (float*)Cout + grow;
#pragma unroll
        for (int s = 0; s < 4; ++s)
          *(f32x4*)(gp + s * 4) = *(const f32x4*)(le + row_l * 128 + c0 + s * 4);
      } else {
        bf16* gp = (bf16*)Cout + grow;
#pragma unroll
        for (int s = 0; s < 4; ++s) {
          f32x4 v = *(const f32x4*)(le + row_l * 128 + c0 + s * 4);
          bf16x4 o;
          o[0] = (bf16)v[0]; o[1] = (bf16)v[1]; o[2] = (bf16)v[2]; o[3] = (bf16)v[3];
          *(bf16x4*)(gp + s * 4) = o;
        }
      }
    }
    __syncthreads();
  }
}

// ---------------------------------------------------------------------------
// RoPE in-place on qkv buffer (cols 0..5119 = q,k heads). One pair per thread.
__global__ __launch_bounds__(256) void rope_kernel(bf16* __restrict__ qkv,
                                                   const float* __restrict__ fc,
                                                   const float* __restrict__ fs) {
  const int p = blockIdx.x * 256 + threadIdx.x;  // 0..2559 pair index
  const int tok = blockIdx.y;                    // 0..4095
  const int s = tok & (SEQ - 1);
  const int dh = p & 63;
  const float c = fc[s * 64 + dh], sn = fs[s * 64 + dh];
  bf16* ptr = qkv + (size_t)tok * QKVN + 2 * p;
  bf16x2 v = *(bf16x2*)ptr;
  const float x0 = (float)v[0], x1 = (float)v[1];
  bf16x2 o;
  o[0] = (bf16)(x0 * c - x1 * sn);
  o[1] = (bf16)(x0 * sn + x1 * c);
  *(bf16x2*)ptr = o;
}

// ---------------------------------------------------------------------------
// V transpose: qkv V columns -> vt[(b*8+g)*HD + d][s]
__global__ __launch_bounds__(256) void tp_v(const bf16* __restrict__ qkv,
                                            bf16* __restrict__ vt) {
  __shared__ bf16 t[32][33];
  const int tx = threadIdx.x, ty = threadIdx.y;  // 32 x 8
  const int s0 = blockIdx.x * 32, d0 = blockIdx.y * 32, bg = blockIdx.z;
  const bf16* src = qkv + (size_t)((bg >> 3) * SEQ) * QKVN + VCOFF + (bg & 7) * HD;
#pragma unroll
  for (int yy = 0; yy < 32; yy += 8)
    t[ty + yy][tx] = src[(size_t)(s0 + ty + yy) * QKVN + d0 + tx];
  __syncthreads();
  bf16* dst = vt + (size_t)bg * HD * SEQ;
#pragma unroll
  for (int yy = 0; yy < 32; yy += 8)
    dst[(size_t)(d0 + ty + yy) * SEQ + s0 + tx] = t[tx][ty + yy];
}

// ---------------------------------------------------------------------------
// Flash attention v3: S^T formulation + register-prefetch pipeline.
// K(kt+1) loaded to regs after B1, V(kt+1) after B2; both ds_written after B4
// -> zero exposed staging latency. P via LDS (verified layout).
__global__ __launch_bounds__(256, 2) void attn_kernel(const bf16* __restrict__ qkv,
                                                      const bf16* __restrict__ vt,
                                                      bf16* __restrict__ aout) {
  __shared__ bf16 lK[128 * 128];  // 32KB: K tile, then P tile
  __shared__ bf16 lV[128 * 128];  // 32KB: V^T tile
  const int tid = threadIdx.x;
  const int w = tid >> 6, lane = tid & 63;
  const int quad = lane >> 4, lq = lane & 15;
  const int qt = (int)gridDim.x - 1 - (int)blockIdx.x;  // heavy blocks first
  const int h = blockIdx.y, b = blockIdx.z;
  const int g = h >> 2;  // kv head (N_REP = 4)
  const int qbase = qt * 128;
  const int wm = w * 32;  // wave's 32 q rows

  const float scale = 0.08838834764831845f;  // 1/sqrt(128)
  const bf16* qp = qkv + (size_t)(b * SEQ + qbase) * QKVN + h * HD;
  bf16x8 qf[2][4];
#pragma unroll
  for (int i2 = 0; i2 < 2; ++i2)
#pragma unroll
    for (int kk = 0; kk < 4; ++kk) {
      bf16x8 v = *(const bf16x8*)(qp + (size_t)(wm + i2 * 16 + lq) * QKVN + kk * 32 + quad * 8);
#pragma unroll
      for (int e = 0; e < 8; ++e) v[e] = (bf16)((float)v[e] * scale);
      qf[i2][kk] = v;
    }

  float mi[2] = {NEG_BIG, NEG_BIG}, li[2] = {0.f, 0.f};
  f32x4 oacc[8][2] = {};  // O^T[d = ds*16+quad*4+r][m = wm+i2*16+lq]

  const bf16* kb0 = qkv + (size_t)(b * SEQ) * QKVN + KCOFF + g * HD;
  const bf16* vt0 = vt + (size_t)(b * NKV + g) * HD * SEQ;

  // prologue: DMA-stage kt=0 (latency exposed once per block)
#pragma unroll
  for (int i = 0; i < 8; ++i) {
    const int c = i * 256 + tid;
    const int row = c >> 4;
    const int lc = (c & 15) ^ (row & 15);
    GLL16(kb0 + (size_t)row * QKVN + lc * 8, lK + (i * 256 + w * 64) * 8);
    GLL16(vt0 + (size_t)row * SEQ + lc * 8, lV + (i * 256 + w * 64) * 8);
  }

  bf16x8 kpre[8], vpre[8];
  for (int kt = 0; kt <= qt; ++kt) {
    __syncthreads();  // B1: staged K/V visible (drains prologue DMA / tail writes)

    // issue K(kt+1) register prefetch (consumed at loop tail, ~full iter ahead)
    if (kt < qt) {
      const bf16* kbn = kb0 + (size_t)((kt + 1) * 128) * QKVN;
#pragma unroll
      for (int i = 0; i < 8; ++i) {
        const int c = i * 256 + tid;
        const int row = c >> 4;
        const int lc = (c & 15) ^ (row & 15);
        kpre[i] = *(const bf16x8*)(kbn + (size_t)row * QKVN + lc * 8);
      }
    }

    // ---- QK^T -> S^T ----
    f32x4 sacc[2][8] = {};
#pragma unroll
    for (int kk = 0; kk < 4; ++kk) {
      bf16x8 kf[8];
#pragma unroll
      for (int ns = 0; ns < 8; ++ns) {
        const int n = ns * 16 + lq;
        kf[ns] = *(const bf16x8*)(lK + n * 128 + (((kk * 4 + quad) ^ (n & 15))) * 8);
      }
#pragma unroll
      for (int i2 = 0; i2 < 2; ++i2)
#pragma unroll
        for (int ns = 0; ns < 8; ++ns)
          sacc[i2][ns] = __builtin_amdgcn_mfma_f32_16x16x32_bf16(kf[ns], qf[i2][kk], sacc[i2][ns], 0, 0, 0);
    }
    __syncthreads();  // B2: lK reads done, safe to overwrite with P

    // issue V(kt+1) register prefetch
    if (kt < qt) {
#pragma unroll
      for (int i = 0; i < 8; ++i) {
        const int c = i * 256 + tid;
        const int row = c >> 4;
        const int lc = (c & 15) ^ (row & 15);
        vpre[i] = *(const bf16x8*)(vt0 + (size_t)row * SEQ + (kt + 1) * 128 + lc * 8);
      }
    }

    // ---- online softmax (per-lane state: column m = lq) ----
    const bool diag = (kt == qt);
#pragma unroll
    for (int i2 = 0; i2 < 2; ++i2) {
      const int m = wm + i2 * 16 + lq;
      if (diag) {
#pragma unroll
        for (int ns = 0; ns < 8; ++ns)
#pragma unroll
          for (int r = 0; r < 4; ++r)
            if (ns * 16 + quad * 4 + r > m) sacc[i2][ns][r] = NEG_BIG;
      }
      float mx = NEG_BIG;
#pragma unroll
      for (int ns = 0; ns < 8; ++ns)
#pragma unroll
        for (int r = 0; r < 4; ++r) mx = fmaxf(mx, sacc[i2][ns][r]);
      mx = fmaxf(mx, __shfl_xor(mx, 16));
      mx = fmaxf(mx, __shfl_xor(mx, 32));
      const float mnew = fmaxf(mi[i2], mx);
      const float al = __expf(mi[i2] - mnew);
      float rs = 0.f;
#pragma unroll
      for (int ns = 0; ns < 8; ++ns)
#pragma unroll
        for (int r = 0; r < 4; ++r) {
          const float e = __expf(sacc[i2][ns][r] - mnew);
          sacc[i2][ns][r] = e;
          rs += e;
        }
      rs += __shfl_xor(rs, 16);
      rs += __shfl_xor(rs, 32);
      li[i2] = li[i2] * al + rs;
      mi[i2] = mnew;
#pragma unroll
      for (int ds = 0; ds < 8; ++ds)
#pragma unroll
        for (int r = 0; r < 4; ++r) oacc[ds][i2][r] *= al;
    }

    // ---- write P [m][n] into lK (b64, swizzled) ----
#pragma unroll
    for (int i2 = 0; i2 < 2; ++i2) {
      const int m = wm + i2 * 16 + lq;
#pragma unroll
      for (int ns = 0; ns < 8; ++ns) {
        bf16x4 p4;
#pragma unroll
        for (int r = 0; r < 4; ++r) p4[r] = (bf16)sacc[i2][ns][r];
        const int n0 = ns * 16 + quad * 4;
        const int pc = (n0 >> 3) ^ (m & 15);
        *(bf16x4*)(lK + m * 128 + pc * 8 + (n0 & 7)) = p4;
      }
    }
    __syncthreads();  // B3: P visible

    // ---- PV: O^T[d][m] += MFMA(A = V^T, B = P) ----
#pragma unroll
    for (int gg = 0; gg < 4; ++gg) {
      bf16x8 pf[2];
#pragma unroll
      for (int i2 = 0; i2 < 2; ++i2) {
        const int m = wm + i2 * 16 + lq;
        pf[i2] = *(const bf16x8*)(lK + m * 128 + (((gg * 4 + quad) ^ (m & 15))) * 8);
      }
#pragma unroll
      for (int ds = 0; ds < 8; ++ds) {
        const int d = ds * 16 + lq;
        bf16x8 vf = *(const bf16x8*)(lV + d * 128 + (((gg * 4 + quad) ^ (d & 15))) * 8);
#pragma unroll
        for (int i2 = 0; i2 < 2; ++i2)
          oacc[ds][i2] = __builtin_amdgcn_mfma_f32_16x16x32_bf16(vf, pf[i2], oacc[ds][i2], 0, 0, 0);
      }
    }
    __syncthreads();  // B4: all lK/lV reads done

    // tail: commit prefetched K/V(kt+1) to LDS (prefetch latency fully hidden)
    if (kt < qt) {
#pragma unroll
      for (int i = 0; i < 8; ++i) {
        *(bf16x8*)(lK + (size_t)(i * 256 + tid) * 8) = kpre[i];
        *(bf16x8*)(lV + (size_t)(i * 256 + tid) * 8) = vpre[i];
      }
    }
  }

  // ---- epilogue: O^T/l -> LDS [m][d] (swizzled) -> coalesced global ----
#pragma unroll
  for (int ds = 0; ds < 8; ++ds)
#pragma unroll
    for (int i2 = 0; i2 < 2; ++i2) {
      const int m = wm + i2 * 16 + lq;
      const float inv = 1.0f / li[i2];
      bf16x4 o4;
#pragma unroll
      for (int r = 0; r < 4; ++r) o4[r] = (bf16)(oacc[ds][i2][r] * inv);
      const int d0 = ds * 16 + quad * 4;
      const int pc = (d0 >> 3) ^ (m & 15);
      *(bf16x4*)(lK + m * 128 + pc * 8 + (d0 & 7)) = o4;
    }
  __syncthreads();
  {
    const int m = tid >> 1, hf = tid & 1;
    bf16* ob = aout + (size_t)(b * SEQ + qbase + m) * (NH * HD) + h * HD + hf * 64;
#pragma unroll
    for (int c = 0; c < 8; ++c) {
      const int lc = hf * 8 + c;
      bf16x8 vv = *(const bf16x8*)(lK + m * 128 + ((lc ^ (m & 15))) * 8);
      *(bf16x8*)(ob + c * 8) = vv;
    }
  }
}

// ---------------------------------------------------------------------------
extern "C" void kernel_launch(void* const* d_in, const int* in_sizes, int n_in,
                              void* d_out, int out_size, void* d_ws, size_t ws_size,
                              hipStream_t stream) {
  (void)in_sizes; (void)n_in; (void)out_size; (void)ws_size;
  const float* x  = (const float*)d_in[0];
  const float* fc = (const float*)d_in[2];
  const float* fs = (const float*)d_in[3];
  const float* wq = (const float*)d_in[6];
  const float* wk = (const float*)d_in[7];
  const float* wv = (const float*)d_in[8];
  const float* wo = (const float*)d_in[9];

  char* ws = (char*)d_ws;
  // layout: [0,48MB) wT (wqkv^T; later wo^T in [0,32MB) + vt in [32,40MB))
  //         [48,80MB) xb (later attn out) | [80,128MB) qkv
  bf16* wT   = (bf16*)ws;
  bf16* vtb  = (bf16*)(ws + 33554432);
  bf16* xb   = (bf16*)(ws + 50331648);
  bf16* qkvb = (bf16*)(ws + 83886080);
  float* outp = (float*)d_out;

  const dim3 tb(32, 8);
  transpose_cvt3<<<dim3(QKVN / 32, DIM / 32), tb, 0, stream>>>(wq, wk, wv, wT);
  cvt_f32_bf16<<<(NTOK * DIM) / 1024, 256, 0, stream>>>(x, xb);
  gemm_bt<false><<<dim3(QKVN / 128, NTOK / 128), 256, 0, stream>>>(xb, wT, qkvb, NTOK, QKVN, DIM);
  rope_kernel<<<dim3(10, NTOK), 256, 0, stream>>>(qkvb, fc, fs);
  tp_v<<<dim3(SEQ / 32, HD / 32, BATCH * NKV), tb, 0, stream>>>(qkvb, vtb);
  transpose_cvt<<<dim3(DIM / 32, (NH * HD) / 32), tb, 0, stream>>>(wo, wT, NH * HD, DIM);
  attn_kernel<<<dim3(SEQ / 128, NH, BATCH), 256, 0, stream>>>(qkvb, vtb, xb);
  gemm_bt<true><<<dim3(DIM / 128, NTOK / 128), 256, 0, stream>>>(xb, wT, outp, NTOK, DIM, NH * HD);
}

// Round 4
// 916.371 us; speedup vs baseline: 1.2926x; 1.2926x over previous
//
#include <hip/hip_runtime.h>
#include <cstdint>

typedef __bf16 bf16;
typedef __bf16 bf16x2 __attribute__((ext_vector_type(2)));
typedef __bf16 bf16x4 __attribute__((ext_vector_type(4)));
typedef __bf16 bf16x8 __attribute__((ext_vector_type(8)));
typedef float  f32x4  __attribute__((ext_vector_type(4)));

#define DIM   4096
#define NH    32
#define NKV   8
#define HD    128
#define BATCH 2
#define SEQ   2048
#define NTOK  (BATCH * SEQ)   // 4096
#define QKVN  6144            // NH*HD + 2*NKV*HD
#define KCOFF 4096            // k column offset in qkv buffer
#define VCOFF 5120            // v column offset
#define NEG_BIG (-1e30f)

// async global->LDS, 16B per lane; LDS dest is wave-uniform base + lane*16
#define GLL16(gp, lp)                                                          \
  __builtin_amdgcn_global_load_lds(                                            \
      (__attribute__((address_space(1))) uint32_t*)(gp),                       \
      (__attribute__((address_space(3))) uint32_t*)(lp), 16, 0, 0)

// ---------------------------------------------------------------------------
// fused wq/wk/wv transpose+convert into concatenated wT[6144][4096]
__global__ __launch_bounds__(256) void transpose_cvt3(const float* __restrict__ wq,
                                                      const float* __restrict__ wk,
                                                      const float* __restrict__ wv,
                                                      bf16* __restrict__ out) {
  __shared__ float t[32][33];
  const int tx = threadIdx.x, ty = threadIdx.y;
  const int n0 = blockIdx.x * 32;  // col in concat [0,6144)
  const int k0 = blockIdx.y * 32;  // row (K dim)
  const float* src; int c0, C;
  if (n0 < 4096)      { src = wq; c0 = n0;        C = 4096; }
  else if (n0 < 5120) { src = wk; c0 = n0 - 4096; C = 1024; }
  else                { src = wv; c0 = n0 - 5120; C = 1024; }
#pragma unroll
  for (int yy = 0; yy < 32; yy += 8)
    t[ty + yy][tx] = src[(size_t)(k0 + ty + yy) * C + c0 + tx];
  __syncthreads();
#pragma unroll
  for (int yy = 0; yy < 32; yy += 8)
    out[(size_t)(n0 + ty + yy) * DIM + k0 + tx] = (bf16)t[tx][ty + yy];
}

// transpose + convert: in[R][C] f32 -> out[C][R] bf16 (for wo)
__global__ __launch_bounds__(256) void transpose_cvt(const float* __restrict__ in,
                                                     bf16* __restrict__ out,
                                                     int R, int C) {
  __shared__ float t[32][33];
  const int tx = threadIdx.x, ty = threadIdx.y;
  const int gx = blockIdx.x * 32, gy = blockIdx.y * 32;
#pragma unroll
  for (int yy = 0; yy < 32; yy += 8)
    t[ty + yy][tx] = in[(size_t)(gy + ty + yy) * C + gx + tx];
  __syncthreads();
#pragma unroll
  for (int yy = 0; yy < 32; yy += 8)
    out[(size_t)(gx + ty + yy) * R + gy + tx] = (bf16)t[tx][ty + yy];
}

// elementwise fp32 -> bf16, 4 per thread
__global__ __launch_bounds__(256) void cvt_f32_bf16(const float* __restrict__ in,
                                                    bf16* __restrict__ out) {
  size_t i = ((size_t)blockIdx.x * 256 + threadIdx.x) * 4;
  f32x4 v = *(const f32x4*)(in + i);
  bf16x4 o;
  o[0] = (bf16)v[0]; o[1] = (bf16)v[1]; o[2] = (bf16)v[2]; o[3] = (bf16)v[3];
  *(bf16x4*)(out + i) = o;
}

// ---------------------------------------------------------------------------
// m97-style GEMM + XOR-swizzled LDS (kills 8-way ds_read_b128 conflicts) +
// LDS-bounce vectorized epilogue. C[M][N] = A[M][K] @ BT[N][K]^T.
template <bool OUTF32>
__global__ __launch_bounds__(256, 4) void gemm_bt(const bf16* __restrict__ A,
                                                  const bf16* __restrict__ BT,
                                                  void* __restrict__ Cout,
                                                  int M, int N, int K) {
  __shared__ bf16 ls[2 * 128 * 32];  // lA = ls, lB = ls+4096; epilogue: f32[32][128]
  bf16* lA = ls;
  bf16* lB = ls + 128 * 32;
  const int tid = threadIdx.x;
  const int w = tid >> 6, lane = tid & 63;
  const int quad = lane >> 4, lq = lane & 15;
  const int bm = blockIdx.y * 128, bn = blockIdx.x * 128;
  const int wm = (w & 1) * 64, wn = (w >> 1) * 64;
  f32x4 acc[4][4] = {};
  const bf16* aBase = A + (size_t)bm * K;
  const bf16* bBase = BT + (size_t)bn * K;
  const int r0 = tid >> 2, o0 = (((tid & 3) ^ ((r0 >> 1) & 3))) * 8;
  const int r1 = r0 + 64,  o1 = ((((tid + 256) & 3) ^ ((r1 >> 1) & 3))) * 8;
  const int sw = (lq >> 1) & 3;  // read-side swizzle

  for (int k0 = 0; k0 < K; k0 += 32) {
    GLL16(aBase + (size_t)r0 * K + k0 + o0, lA + (w * 64) * 8);
    GLL16(aBase + (size_t)r1 * K + k0 + o1, lA + (256 + w * 64) * 8);
    GLL16(bBase + (size_t)r0 * K + k0 + o0, lB + (w * 64) * 8);
    GLL16(bBase + (size_t)r1 * K + k0 + o1, lB + (256 + w * 64) * 8);
    __syncthreads();
    bf16x8 af[4], bfr[4];
#pragma unroll
    for (int i = 0; i < 4; ++i)
      af[i] = *(const bf16x8*)(lA + (wm + i * 16 + lq) * 32 + (quad ^ sw) * 8);
#pragma unroll
    for (int j = 0; j < 4; ++j)
      bfr[j] = *(const bf16x8*)(lB + (wn + j * 16 + lq) * 32 + (quad ^ sw) * 8);
#pragma unroll
    for (int i = 0; i < 4; ++i)
#pragma unroll
      for (int j = 0; j < 4; ++j)
        acc[i][j] = __builtin_amdgcn_mfma_f32_16x16x32_bf16(af[i], bfr[j], acc[i][j], 0, 0, 0);
    __syncthreads();
  }

  // epilogue: bounce 32-row slabs through LDS -> vectorized global stores
  float* le = (float*)ls;  // 32 x 128 f32 = 16 KB
#pragma unroll
  for (int p = 0; p < 4; ++p) {
    if ((w & 1) == (p >> 1)) {
#pragma unroll
      for (int ii = 0; ii < 2; ++ii) {
        const int i = (p & 1) * 2 + ii;
#pragma unroll
        for (int j = 0; j < 4; ++j)
#pragma unroll
          for (int r = 0; r < 4; ++r)
            le[(ii * 16 + quad * 4 + r) * 128 + wn + j * 16 + lq] = acc[i][j][r];
      }
    }
    __syncthreads();
    {
      const int row_l = tid >> 3, c0 = (tid & 7) * 16;
      const size_t grow = (size_t)(bm + p * 32 + row_l) * N + bn + c0;
      if (OUTF32) {
        float* gp = (float*)Cout + grow;
#pragma unroll
        for (int s = 0; s < 4; ++s)
          *(f32x4*)(gp + s * 4) = *(const f32x4*)(le + row_l * 128 + c0 + s * 4);
      } else {
        bf16* gp = (bf16*)Cout + grow;
#pragma unroll
        for (int s = 0; s < 4; ++s) {
          f32x4 v = *(const f32x4*)(le + row_l * 128 + c0 + s * 4);
          bf16x4 o;
          o[0] = (bf16)v[0]; o[1] = (bf16)v[1]; o[2] = (bf16)v[2]; o[3] = (bf16)v[3];
          *(bf16x4*)(gp + s * 4) = o;
        }
      }
    }
    __syncthreads();
  }
}

// ---------------------------------------------------------------------------
// RoPE in-place on qkv buffer (cols 0..5119 = q,k heads). One pair per thread.
__global__ __launch_bounds__(256) void rope_kernel(bf16* __restrict__ qkv,
                                                   const float* __restrict__ fc,
                                                   const float* __restrict__ fs) {
  const int p = blockIdx.x * 256 + threadIdx.x;  // 0..2559 pair index
  const int tok = blockIdx.y;                    // 0..4095
  const int s = tok & (SEQ - 1);
  const int dh = p & 63;
  const float c = fc[s * 64 + dh], sn = fs[s * 64 + dh];
  bf16* ptr = qkv + (size_t)tok * QKVN + 2 * p;
  bf16x2 v = *(bf16x2*)ptr;
  const float x0 = (float)v[0], x1 = (float)v[1];
  bf16x2 o;
  o[0] = (bf16)(x0 * c - x1 * sn);
  o[1] = (bf16)(x0 * sn + x1 * c);
  *(bf16x2*)ptr = o;
}

// ---------------------------------------------------------------------------
// V transpose: qkv V columns -> vt[(b*8+g)*HD + d][s]
__global__ __launch_bounds__(256) void tp_v(const bf16* __restrict__ qkv,
                                            bf16* __restrict__ vt) {
  __shared__ bf16 t[32][33];
  const int tx = threadIdx.x, ty = threadIdx.y;  // 32 x 8
  const int s0 = blockIdx.x * 32, d0 = blockIdx.y * 32, bg = blockIdx.z;
  const bf16* src = qkv + (size_t)((bg >> 3) * SEQ) * QKVN + VCOFF + (bg & 7) * HD;
#pragma unroll
  for (int yy = 0; yy < 32; yy += 8)
    t[ty + yy][tx] = src[(size_t)(s0 + ty + yy) * QKVN + d0 + tx];
  __syncthreads();
  bf16* dst = vt + (size_t)bg * HD * SEQ;
#pragma unroll
  for (int yy = 0; yy < 32; yy += 8)
    dst[(size_t)(d0 + ty + yy) * SEQ + s0 + tx] = t[tx][ty + yy];
}

// ---------------------------------------------------------------------------
// Flash attention (round-2 known-good): S^T formulation, in-loop DMA staging.
// No register prefetch — that spilled (R3: WRITE_SIZE 772MB). 2 blocks/CU
// provide the cross-block latency overlap instead.
__global__ __launch_bounds__(256, 2) void attn_kernel(const bf16* __restrict__ qkv,
                                                      const bf16* __restrict__ vt,
                                                      bf16* __restrict__ aout) {
  __shared__ bf16 lK[128 * 128];  // 32KB: K tile, then P tile
  __shared__ bf16 lV[128 * 128];  // 32KB: V^T tile
  const int tid = threadIdx.x;
  const int w = tid >> 6, lane = tid & 63;
  const int quad = lane >> 4, lq = lane & 15;
  const int qt = (int)gridDim.x - 1 - (int)blockIdx.x;  // heavy blocks first
  const int h = blockIdx.y, b = blockIdx.z;
  const int g = h >> 2;  // kv head (N_REP = 4)
  const int qbase = qt * 128;
  const int wm = w * 32;  // wave's 32 q rows

  const float scale = 0.08838834764831845f;  // 1/sqrt(128)
  const bf16* qp = qkv + (size_t)(b * SEQ + qbase) * QKVN + h * HD;
  bf16x8 qf[2][4];
#pragma unroll
  for (int i2 = 0; i2 < 2; ++i2)
#pragma unroll
    for (int kk = 0; kk < 4; ++kk) {
      bf16x8 v = *(const bf16x8*)(qp + (size_t)(wm + i2 * 16 + lq) * QKVN + kk * 32 + quad * 8);
#pragma unroll
      for (int e = 0; e < 8; ++e) v[e] = (bf16)((float)v[e] * scale);
      qf[i2][kk] = v;
    }

  float mi[2] = {NEG_BIG, NEG_BIG}, li[2] = {0.f, 0.f};
  f32x4 oacc[8][2] = {};  // O^T[d = ds*16+quad*4+r][m = wm+i2*16+lq]

  const bf16* kb0 = qkv + (size_t)(b * SEQ) * QKVN + KCOFF + g * HD;
  const bf16* vt0 = vt + (size_t)(b * NKV + g) * HD * SEQ;

  for (int kt = 0; kt <= qt; ++kt) {
    // ---- stage K tile [n][d] and V^T tile [d][n], both chunk-swizzled ----
    const bf16* kb = kb0 + (size_t)(kt * 128) * QKVN;
#pragma unroll
    for (int i = 0; i < 8; ++i) {
      const int c = i * 256 + tid;        // physical 16B chunk 0..2047
      const int row = c >> 4;             // n for K, d for V^T
      const int lc = (c & 15) ^ (row & 15);
      GLL16(kb + (size_t)row * QKVN + lc * 8, lK + (i * 256 + w * 64) * 8);
      GLL16(vt0 + (size_t)row * SEQ + kt * 128 + lc * 8, lV + (i * 256 + w * 64) * 8);
    }
    __syncthreads();  // B1: tiles ready

    // ---- QK^T -> S^T: sacc[i2][ns], n = ns*16+quad*4+r, m = wm+i2*16+lq ----
    f32x4 sacc[2][8] = {};
#pragma unroll
    for (int kk = 0; kk < 4; ++kk) {
      bf16x8 kf[8];
#pragma unroll
      for (int ns = 0; ns < 8; ++ns) {
        const int n = ns * 16 + lq;
        kf[ns] = *(const bf16x8*)(lK + n * 128 + (((kk * 4 + quad) ^ (n & 15))) * 8);
      }
#pragma unroll
      for (int i2 = 0; i2 < 2; ++i2)
#pragma unroll
        for (int ns = 0; ns < 8; ++ns)
          sacc[i2][ns] = __builtin_amdgcn_mfma_f32_16x16x32_bf16(kf[ns], qf[i2][kk], sacc[i2][ns], 0, 0, 0);
    }
    __syncthreads();  // B2: lK reads done, safe to overwrite with P

    // ---- online softmax (per-lane state: column m = lq) ----
    const bool diag = (kt == qt);
#pragma unroll
    for (int i2 = 0; i2 < 2; ++i2) {
      const int m = wm + i2 * 16 + lq;
      if (diag) {
#pragma unroll
        for (int ns = 0; ns < 8; ++ns)
#pragma unroll
          for (int r = 0; r < 4; ++r)
            if (ns * 16 + quad * 4 + r > m) sacc[i2][ns][r] = NEG_BIG;
      }
      float mx = NEG_BIG;
#pragma unroll
      for (int ns = 0; ns < 8; ++ns)
#pragma unroll
        for (int r = 0; r < 4; ++r) mx = fmaxf(mx, sacc[i2][ns][r]);
      mx = fmaxf(mx, __shfl_xor(mx, 16));
      mx = fmaxf(mx, __shfl_xor(mx, 32));
      const float mnew = fmaxf(mi[i2], mx);
      const float al = __expf(mi[i2] - mnew);
      float rs = 0.f;
#pragma unroll
      for (int ns = 0; ns < 8; ++ns)
#pragma unroll
        for (int r = 0; r < 4; ++r) {
          const float e = __expf(sacc[i2][ns][r] - mnew);
          sacc[i2][ns][r] = e;
          rs += e;
        }
      rs += __shfl_xor(rs, 16);
      rs += __shfl_xor(rs, 32);
      li[i2] = li[i2] * al + rs;
      mi[i2] = mnew;
#pragma unroll
      for (int ds = 0; ds < 8; ++ds)
#pragma unroll
        for (int r = 0; r < 4; ++r) oacc[ds][i2][r] *= al;
    }

    // ---- write P [m][n] into lK (b64, swizzled) ----
#pragma unroll
    for (int i2 = 0; i2 < 2; ++i2) {
      const int m = wm + i2 * 16 + lq;
#pragma unroll
      for (int ns = 0; ns < 8; ++ns) {
        bf16x4 p4;
#pragma unroll
        for (int r = 0; r < 4; ++r) p4[r] = (bf16)sacc[i2][ns][r];
        const int n0 = ns * 16 + quad * 4;
        const int pc = (n0 >> 3) ^ (m & 15);
        *(bf16x4*)(lK + m * 128 + pc * 8 + (n0 & 7)) = p4;
      }
    }
    __syncthreads();  // B3: P visible

    // ---- PV: O^T[d][m] += MFMA(A = V^T, B = P) ----
#pragma unroll
    for (int gg = 0; gg < 4; ++gg) {
      bf16x8 pf[2];
#pragma unroll
      for (int i2 = 0; i2 < 2; ++i2) {
        const int m = wm + i2 * 16 + lq;
        pf[i2] = *(const bf16x8*)(lK + m * 128 + (((gg * 4 + quad) ^ (m & 15))) * 8);
      }
#pragma unroll
      for (int ds = 0; ds < 8; ++ds) {
        const int d = ds * 16 + lq;
        bf16x8 vf = *(const bf16x8*)(lV + d * 128 + (((gg * 4 + quad) ^ (d & 15))) * 8);
#pragma unroll
        for (int i2 = 0; i2 < 2; ++i2)
          oacc[ds][i2] = __builtin_amdgcn_mfma_f32_16x16x32_bf16(vf, pf[i2], oacc[ds][i2], 0, 0, 0);
      }
    }
    __syncthreads();  // B4: lK/lV reads done before next staging
  }

  // ---- epilogue: O^T/l -> LDS [m][d] (swizzled) -> coalesced global ----
#pragma unroll
  for (int ds = 0; ds < 8; ++ds)
#pragma unroll
    for (int i2 = 0; i2 < 2; ++i2) {
      const int m = wm + i2 * 16 + lq;
      const float inv = 1.0f / li[i2];
      bf16x4 o4;
#pragma unroll
      for (int r = 0; r < 4; ++r) o4[r] = (bf16)(oacc[ds][i2][r] * inv);
      const int d0 = ds * 16 + quad * 4;
      const int pc = (d0 >> 3) ^ (m & 15);
      *(bf16x4*)(lK + m * 128 + pc * 8 + (d0 & 7)) = o4;
    }
  __syncthreads();
  {
    const int m = tid >> 1, hf = tid & 1;
    bf16* ob = aout + (size_t)(b * SEQ + qbase + m) * (NH * HD) + h * HD + hf * 64;
#pragma unroll
    for (int c = 0; c < 8; ++c) {
      const int lc = hf * 8 + c;
      bf16x8 vv = *(const bf16x8*)(lK + m * 128 + ((lc ^ (m & 15))) * 8);
      *(bf16x8*)(ob + c * 8) = vv;
    }
  }
}

// ---------------------------------------------------------------------------
extern "C" void kernel_launch(void* const* d_in, const int* in_sizes, int n_in,
                              void* d_out, int out_size, void* d_ws, size_t ws_size,
                              hipStream_t stream) {
  (void)in_sizes; (void)n_in; (void)out_size; (void)ws_size;
  const float* x  = (const float*)d_in[0];
  const float* fc = (const float*)d_in[2];
  const float* fs = (const float*)d_in[3];
  const float* wq = (const float*)d_in[6];
  const float* wk = (const float*)d_in[7];
  const float* wv = (const float*)d_in[8];
  const float* wo = (const float*)d_in[9];

  char* ws = (char*)d_ws;
  // layout: [0,48MB) wT (wqkv^T; later wo^T in [0,32MB) + vt in [32,40MB))
  //         [48,80MB) xb (later attn out) | [80,128MB) qkv
  bf16* wT   = (bf16*)ws;
  bf16* vtb  = (bf16*)(ws + 33554432);
  bf16* xb   = (bf16*)(ws + 50331648);
  bf16* qkvb = (bf16*)(ws + 83886080);
  float* outp = (float*)d_out;

  const dim3 tb(32, 8);
  transpose_cvt3<<<dim3(QKVN / 32, DIM / 32), tb, 0, stream>>>(wq, wk, wv, wT);
  cvt_f32_bf16<<<(NTOK * DIM) / 1024, 256, 0, stream>>>(x, xb);
  gemm_bt<false><<<dim3(QKVN / 128, NTOK / 128), 256, 0, stream>>>(xb, wT, qkvb, NTOK, QKVN, DIM);
  rope_kernel<<<dim3(10, NTOK), 256, 0, stream>>>(qkvb, fc, fs);
  tp_v<<<dim3(SEQ / 32, HD / 32, BATCH * NKV), tb, 0, stream>>>(qkvb, vtb);
  transpose_cvt<<<dim3(DIM / 32, (NH * HD) / 32), tb, 0, stream>>>(wo, wT, NH * HD, DIM);
  attn_kernel<<<dim3(SEQ / 128, NH, BATCH), 256, 0, stream>>>(qkvb, vtb, xb);
  gemm_bt<true><<<dim3(DIM / 128, NTOK / 128), 256, 0, stream>>>(xb, wT, outp, NTOK, DIM, NH * HD);
}